// Round 16
// baseline (4960.905 us; speedup 1.0000x reference)
//
#include <hip/hip_runtime.h>

#define T_STEPS 1000
#define NIN     128
#define NREC    512
#define NBATCH  64
#define ALPHA   0.2f

typedef _Float16 f16x8 __attribute__((ext_vector_type(8)));
typedef float    f32x4 __attribute__((ext_vector_type(4)));

// d_ws layout: [0, 512KB) = Wt fp16 (512x512, TRANSPOSED: Wt[j][k] = W_eff[k][j])
#define WS_WT_BYTES (NREC * NREC * 2)

// lgkm-only barrier (proven r6-r15): drains LDS ops, NOT vmcnt.
#define LDS_BARRIER() do {                                        \
    asm volatile("s_waitcnt lgkmcnt(0)" ::: "memory");            \
    __builtin_amdgcn_s_barrier();                                 \
    asm volatile("" ::: "memory");                                \
} while (0)

// ---------------------------------------------------------------------------
// Wt[j][k] = (fp16)( ei[k] * w_rec[k][j] * autapse[k][j] )
// ---------------------------------------------------------------------------
__global__ void weff_f16_kernel(const float* __restrict__ w_rec,
                                const float* __restrict__ ei_mask,
                                const float* __restrict__ autapse,
                                _Float16* __restrict__ wt) {
    int idx = blockIdx.x * blockDim.x + threadIdx.x;   // idx = j*512 + k
    if (idx < NREC * NREC) {
        int j = idx >> 9;
        int k = idx & (NREC - 1);
        float v = ei_mask[k * NREC + k] * w_rec[k * NREC + j]
                  * autapse[k * NREC + j];
        wt[idx] = (_Float16)v;
    }
}

// fp32 W_eff for the fallback path
__global__ void weff_kernel(const float* __restrict__ w_rec,
                            const float* __restrict__ ei_mask,
                            const float* __restrict__ autapse,
                            float* __restrict__ w_eff) {
    int idx = blockIdx.x * blockDim.x + threadIdx.x;
    if (idx < NREC * NREC) {
        int row = idx >> 9;
        float ei = ei_mask[row * NREC + row];
        w_eff[idx] = ei * w_rec[idx] * autapse[idx];
    }
}

// ---------------------------------------------------------------------------
// inp_all[m][j] = sum_k x[m][k] * w_in[k][j] + b_rec[j]   (into d_out)
// ---------------------------------------------------------------------------
__global__ __launch_bounds__(1024) void gemm_in_kernel(
        const float* __restrict__ x,
        const float* __restrict__ w_in,
        const float* __restrict__ b_rec,
        float* __restrict__ io) {
    __shared__ float xs[32][NIN];

    const int tid = threadIdx.x;
    const int m0  = blockIdx.x * 32;

    {
        const float4* src = reinterpret_cast<const float4*>(x + (size_t)m0 * NIN);
        reinterpret_cast<float4*>(&xs[0][0])[tid] = src[tid];
    }
    __syncthreads();

    const int j0 = tid & 255;
    const int j1 = j0 + 256;
    const int rg = tid >> 8;

    float acc[8][2];
#pragma unroll
    for (int i = 0; i < 8; ++i) { acc[i][0] = 0.f; acc[i][1] = 0.f; }

#pragma unroll 4
    for (int k = 0; k < NIN; ++k) {
        float wv0 = w_in[k * NREC + j0];
        float wv1 = w_in[k * NREC + j1];
#pragma unroll
        for (int i = 0; i < 8; ++i) {
            float xv = xs[rg * 8 + i][k];
            acc[i][0] = fmaf(xv, wv0, acc[i][0]);
            acc[i][1] = fmaf(xv, wv1, acc[i][1]);
        }
    }

    const float br0 = b_rec[j0];
    const float br1 = b_rec[j1];
#pragma unroll
    for (int i = 0; i < 8; ++i) {
        size_t ro = (size_t)(m0 + rg * 8 + i) * NREC;
        io[ro + j0] = acc[i][0] + br0;
        io[ro + j1] = acc[i][1] + br1;
    }
}

// ---------------------------------------------------------------------------
// Recurrence: ONE block per batch, NO inter-block communication.
// 512 threads = 8 waves. Wave w: kh = w>>2 (K-half of 256), ng = w&3
// (N-slice of 128 cols). Full W_eff in registers as fp16 MFMA B-fragments,
// wf[8][8] = 256 regs/lane, PINNED via asm (r15's failure: without the pin
// the compiler sinks the loads into the loop -> 512KB/step L2 re-stream).
//   B-frag (16x16x32): lane l holds B[8*(l>>4)+j][l&15], j=0..7
//   A-frag: row 0 = h (lanes with l&15==0), rows 1-15 zero (M=1 GEMV)
//   C/D (m89): col=lane&15, row=(lane>>4)*4+reg -> row 0 = lanes 0-15 reg 0
// Per step: 8 ds_read_b128 A-build, 64 MFMA, row-0 extract -> part[kh],
// lgkm barrier, 512-thread update (fp32 state, fp16 only as MFMA input),
// io store + next-row prefetch, lgkm barrier.
// ---------------------------------------------------------------------------
__global__ __launch_bounds__(512, 1) void rnn_mfma(
        const _Float16* __restrict__ Wt,
        const float* __restrict__ noise,
        float* __restrict__ io) {
    __shared__ _Float16 hl[NREC];
    __shared__ float part[2][NREC];

    const int tid  = threadIdx.x;
    const int b    = blockIdx.x;
    const int w    = tid >> 6;
    const int ln   = tid & 63;
    const int lrow = ln & 15;
    const int lkb  = ln >> 4;              // k-block within fragment (0..3)
    const int kh   = w >> 2;               // K-half (0/1)
    const int ng   = w & 3;                // N-slice (0..3)

    // ---- one-time: load this wave's 64 W fragments, then PIN them ----
    f16x8 wf[8][8];
#pragma unroll
    for (int kt = 0; kt < 8; ++kt)
#pragma unroll
        for (int nt = 0; nt < 8; ++nt) {
            const int col = ng * 128 + nt * 16 + lrow;
            const int kb  = kh * 256 + kt * 32 + lkb * 8;
            wf[kt][nt] = *reinterpret_cast<const f16x8*>(
                &Wt[(size_t)col * NREC + kb]);
        }
#pragma unroll
    for (int kt = 0; kt < 8; ++kt)
#pragma unroll
        for (int nt = 0; nt < 8; ++nt)
            asm volatile("" : "+v"(wf[kt][nt]));   // forbid remat/re-load

    hl[tid] = (_Float16)0.f;
    float hj = 0.f;
    const size_t iobase = (size_t)b * T_STEPS * NREC + tid;
    float inp = io[iobase];
    float nz  = noise[iobase];
    __syncthreads();

    for (int t = 0; t < T_STEPS; ++t) {
        // ---- A-fragments: row 0 = h slice, rows 1-15 = 0 ----
        f16x8 af[8];
#pragma unroll
        for (int kt = 0; kt < 8; ++kt) {
            f16x8 a;
#pragma unroll
            for (int j = 0; j < 8; ++j) a[j] = (_Float16)0.f;
            if (lrow == 0)
                a = *reinterpret_cast<const f16x8*>(
                    &hl[kh * 256 + kt * 32 + lkb * 8]);
            af[kt] = a;
        }

        // ---- 64 MFMA: C[0][col] = sum_k h[k] * W[k][col] ----
        f32x4 cc[8];
#pragma unroll
        for (int nt = 0; nt < 8; ++nt) {
            cc[nt][0] = 0.f; cc[nt][1] = 0.f;
            cc[nt][2] = 0.f; cc[nt][3] = 0.f;
        }
#pragma unroll
        for (int kt = 0; kt < 8; ++kt)
#pragma unroll
            for (int nt = 0; nt < 8; ++nt)
                cc[nt] = __builtin_amdgcn_mfma_f32_16x16x32_f16(
                    af[kt], wf[kt][nt], cc[nt], 0, 0, 0);

        // ---- extract row 0 (lanes 0-15, reg 0) into part[kh] ----
        if (ln < 16) {
#pragma unroll
            for (int nt = 0; nt < 8; ++nt)
                part[kh][ng * 128 + nt * 16 + ln] = cc[nt][0];
        }
        LDS_BARRIER();                     // B1: partials ready

        // ---- update: every thread owns one column ----
        {
            float pre  = part[0][tid] + part[1][tid] + inp + nz;
            float hnew = (1.f - ALPHA) * hj + ALPHA * fmaxf(pre, 0.f);
            hj = hnew;
            hl[tid] = (_Float16)hnew;      // fp16 ONLY as MFMA input
            io[iobase + (size_t)t * NREC] = hnew;
            if (t + 1 < T_STEPS) {         // prefetch next row (same-thread)
                inp = io[iobase + (size_t)(t + 1) * NREC];
                nz  = noise[iobase + (size_t)(t + 1) * NREC];
            }
        }
        LDS_BARRIER();                     // B2: hl ready for next A-build
    }
}

// ---------------------------------------------------------------------------
// Fallback (round-1 kernel, fp32) if ws_size is too small for Wt.
// ---------------------------------------------------------------------------
__global__ __launch_bounds__(1024) void rnn_kernel(
        const float* __restrict__ W,
        const float* __restrict__ noise,
        float* __restrict__ io) {
    __shared__ float h[NREC];
    __shared__ float part2[NREC];

    const int tid  = threadIdx.x;
    const int j    = tid & (NREC - 1);
    const int half = tid >> 9;
    const int b    = blockIdx.x;

    if (tid < NREC) h[tid] = 0.f;
    float hj = 0.f;
    __syncthreads();

    const int kb = half * 256;
    const float* wp = W + (size_t)kb * NREC + j;
    const size_t base = (size_t)b * T_STEPS * NREC + j;

    for (int t = 0; t < T_STEPS; ++t) {
        const size_t off = base + (size_t)t * NREC;
        float acc = (half == 0) ? (io[off] + noise[off]) : 0.f;
#pragma unroll
        for (int ku = 0; ku < 256; ku += 16) {
            float wv[16];
#pragma unroll
            for (int u = 0; u < 16; ++u) wv[u] = wp[(size_t)(ku + u) * NREC];
#pragma unroll
            for (int u = 0; u < 16; ++u) acc = fmaf(h[kb + ku + u], wv[u], acc);
        }
        if (half == 1) part2[j] = acc;
        __syncthreads();
        if (half == 0) {
            float pre  = acc + part2[j];
            float hnew = (1.f - ALPHA) * hj + ALPHA * fmaxf(pre, 0.f);
            io[off] = hnew;
            h[j] = hnew;
            hj = hnew;
        }
        __syncthreads();
    }
}

// ---------------------------------------------------------------------------
extern "C" void kernel_launch(void* const* d_in, const int* in_sizes, int n_in,
                              void* d_out, int out_size, void* d_ws, size_t ws_size,
                              hipStream_t stream) {
    const float* x       = (const float*)d_in[0];
    const float* w_in    = (const float*)d_in[1];
    const float* w_rec   = (const float*)d_in[2];
    const float* b_rec   = (const float*)d_in[3];
    const float* ei_mask = (const float*)d_in[4];
    const float* autapse = (const float*)d_in[5];
    const float* noise   = (const float*)d_in[6];
    float* out = (float*)d_out;

    gemm_in_kernel<<<dim3(64000 / 32), dim3(1024), 0, stream>>>(
        x, w_in, b_rec, out);

    if (ws_size >= (size_t)WS_WT_BYTES) {
        _Float16* Wt = (_Float16*)d_ws;
        weff_f16_kernel<<<dim3((NREC * NREC + 255) / 256), dim3(256),
                          0, stream>>>(w_rec, ei_mask, autapse, Wt);
        rnn_mfma<<<dim3(NBATCH), dim3(512), 0, stream>>>(Wt, noise, out);
    } else {
        float* W = (float*)d_ws;
        weff_kernel<<<dim3((NREC * NREC + 255) / 256), dim3(256),
                      0, stream>>>(w_rec, ei_mask, autapse, W);
        rnn_kernel<<<dim3(NBATCH), dim3(1024), 0, stream>>>(W, noise, out);
    }
}

// Round 17
// 1690.155 us; speedup vs baseline: 2.9352x; 2.9352x over previous
//
#include <hip/hip_runtime.h>

#define T_STEPS 1000
#define NIN     128
#define NREC    512
#define NBATCH  64
#define ALPHA   0.2f
#define NHALF   256        // columns per block (N-half)

typedef _Float16 f16x8 __attribute__((ext_vector_type(8)));
typedef float    f32x4 __attribute__((ext_vector_type(4)));

// d_ws layout (bytes):
//   [0, 512KB)         Wt fp16 (512x512 transposed; fp32 fallback W uses 1MB)
//   [1MB, +512KB)      comm  (LLC slots): 2 parities x 64 x 512 u64 {tag,h}
//   [1.5MB, +512KB)    comm2 (L2 slots):  same layout
#define WS_WT_BYTES   (NREC * NREC * 2)
#define WS_COMM_OFF   (1u << 20)
#define COMM_U64      (NBATCH * NREC)
#define COMM_BYTES    (2 * COMM_U64 * 8)
#define WS_COMM2_OFF  (WS_COMM_OFF + COMM_BYTES)
#define WS_NEEDED     (WS_COMM2_OFF + COMM_BYTES)

// lgkm-only barrier (proven r6-r16)
#define LDS_BARRIER() do {                                        \
    asm volatile("s_waitcnt lgkmcnt(0)" ::: "memory");            \
    __builtin_amdgcn_s_barrier();                                 \
    asm volatile("" ::: "memory");                                \
} while (0)

// --- comm primitives (proven r10-r14) ------------------------------------
__device__ __forceinline__ unsigned long long ld_l2(
        const unsigned long long* p) {
    unsigned long long r;
    asm volatile("global_load_dwordx2 %0, %1, off sc0\n\t"
                 "s_waitcnt vmcnt(0)"
                 : "=v"(r) : "v"(p) : "memory");
    return r;
}
__device__ __forceinline__ void st_l2(unsigned long long* p,
                                      unsigned long long v) {
    asm volatile("global_store_dwordx2 %0, %1, off"
                 :: "v"(p), "v"(v) : "memory");
}
__device__ __forceinline__ unsigned long long ld_llc(
        const unsigned long long* p) {
    return __hip_atomic_load(p, __ATOMIC_RELAXED, __HIP_MEMORY_SCOPE_AGENT);
}
__device__ __forceinline__ void st_llc(unsigned long long* p,
                                       unsigned long long v) {
    __hip_atomic_store(p, v, __ATOMIC_RELAXED, __HIP_MEMORY_SCOPE_AGENT);
}

// ---------------------------------------------------------------------------
// Wt[j][k] = (fp16)( ei[k] * w_rec[k][j] * autapse[k][j] )
// ---------------------------------------------------------------------------
__global__ void weff_f16_kernel(const float* __restrict__ w_rec,
                                const float* __restrict__ ei_mask,
                                const float* __restrict__ autapse,
                                _Float16* __restrict__ wt) {
    int idx = blockIdx.x * blockDim.x + threadIdx.x;   // idx = j*512 + k
    if (idx < NREC * NREC) {
        int j = idx >> 9;
        int k = idx & (NREC - 1);
        float v = ei_mask[k * NREC + k] * w_rec[k * NREC + j]
                  * autapse[k * NREC + j];
        wt[idx] = (_Float16)v;
    }
}

// fp32 W_eff for the fallback path
__global__ void weff_kernel(const float* __restrict__ w_rec,
                            const float* __restrict__ ei_mask,
                            const float* __restrict__ autapse,
                            float* __restrict__ w_eff) {
    int idx = blockIdx.x * blockDim.x + threadIdx.x;
    if (idx < NREC * NREC) {
        int row = idx >> 9;
        float ei = ei_mask[row * NREC + row];
        w_eff[idx] = ei * w_rec[idx] * autapse[idx];
    }
}

// ---------------------------------------------------------------------------
// inp_all[m][j] = sum_k x[m][k] * w_in[k][j] + b_rec[j]   (into d_out)
// ---------------------------------------------------------------------------
__global__ __launch_bounds__(1024) void gemm_in_kernel(
        const float* __restrict__ x,
        const float* __restrict__ w_in,
        const float* __restrict__ b_rec,
        float* __restrict__ io) {
    __shared__ float xs[32][NIN];

    const int tid = threadIdx.x;
    const int m0  = blockIdx.x * 32;

    {
        const float4* src = reinterpret_cast<const float4*>(x + (size_t)m0 * NIN);
        reinterpret_cast<float4*>(&xs[0][0])[tid] = src[tid];
    }
    __syncthreads();

    const int j0 = tid & 255;
    const int j1 = j0 + 256;
    const int rg = tid >> 8;

    float acc[8][2];
#pragma unroll
    for (int i = 0; i < 8; ++i) { acc[i][0] = 0.f; acc[i][1] = 0.f; }

#pragma unroll 4
    for (int k = 0; k < NIN; ++k) {
        float wv0 = w_in[k * NREC + j0];
        float wv1 = w_in[k * NREC + j1];
#pragma unroll
        for (int i = 0; i < 8; ++i) {
            float xv = xs[rg * 8 + i][k];
            acc[i][0] = fmaf(xv, wv0, acc[i][0]);
            acc[i][1] = fmaf(xv, wv1, acc[i][1]);
        }
    }

    const float br0 = b_rec[j0];
    const float br1 = b_rec[j1];
#pragma unroll
    for (int i = 0; i < 8; ++i) {
        size_t ro = (size_t)(m0 + rg * 8 + i) * NREC;
        io[ro + j0] = acc[i][0] + br0;
        io[ro + j1] = acc[i][1] + br1;
    }
}

// ---------------------------------------------------------------------------
// Recurrence: 2 blocks per batch (N-halves), W-half resident in registers.
// 128 blocks: n = (bid>>3)&1, b = (bid&7) + 8*(bid>>4)  -> partner bids
// differ by 8 => same bid%8 => same XCD (round-robin, r10-verified).
// 512 thr = 8 waves: kh = w>>2 (K-half), ns = w&3 (N-slice of 64).
// wf[8][4] = 32 frags = 128 VGPRs/lane; total ~210 < 256 cap (LB(512,2)).
//   B-frag: lane l holds B[8*(l>>4)+j][l&15];  A-frag row0 = h (M=1 GEMV)
//   C/D (m89): row0 = lanes 0-15, reg 0
// Per step: A-build (8 ds_read_b128 from fp16 hl[512]), 32 MFMA, extract
// row0 -> part[kh][256], B1; waves0-3 (tid<256): update col, publish
// {t+1,h} dual-path, io store, prefetch; waves4-7: poll partner's 256
// slots (tag>=t+1), deposit hl; B2. Deadlock-free (publish before wait).
// ---------------------------------------------------------------------------
__global__ __launch_bounds__(512, 2) void rnn_mfma2(
        const _Float16* __restrict__ Wt,
        const float* __restrict__ noise,
        float* __restrict__ io,
        unsigned long long* __restrict__ comm,     // LLC slots
        unsigned long long* __restrict__ comm2) {  // L2 slots
    __shared__ _Float16 hl[NREC];                  // full h_t (fp16)
    __shared__ float part[2][NHALF];               // K-half partials

    const int tid  = threadIdx.x;
    const int bid  = blockIdx.x;
    const int n    = (bid >> 3) & 1;               // N-half of this block
    const int b    = (bid & 7) + 8 * (bid >> 4);   // batch
    const int w    = tid >> 6;
    const int ln   = tid & 63;
    const int lrow = ln & 15;
    const int lkb  = ln >> 4;
    const int kh   = w >> 2;                       // K-half (0/1)
    const int ns   = w & 3;                        // N-slice of 64

    // ---- one-time: load this wave's 32 W fragments (128 VGPRs), pin ----
    f16x8 wf[8][4];
#pragma unroll
    for (int kt = 0; kt < 8; ++kt)
#pragma unroll
        for (int nt = 0; nt < 4; ++nt) {
            const int col = n * NHALF + ns * 64 + nt * 16 + lrow;
            const int kb  = kh * 256 + kt * 32 + lkb * 8;
            wf[kt][nt] = *reinterpret_cast<const f16x8*>(
                &Wt[(size_t)col * NREC + kb]);
        }
#pragma unroll
    for (int kt = 0; kt < 8; ++kt)
#pragma unroll
        for (int nt = 0; nt < 4; ++nt)
            asm volatile("" : "+v"(wf[kt][nt]));

    // roles
    const int  uc   = tid;                         // update col (tid<256)
    const int  pc   = tid - NHALF;                 // poll col   (tid>=256)
    const size_t iobase = (size_t)b * T_STEPS * NREC + n * NHALF + uc;
    unsigned long long* cwr  = comm  + (size_t)b * NREC + n * NHALF + uc;
    unsigned long long* cwr2 = comm2 + (size_t)b * NREC + n * NHALF + uc;
    const unsigned long long* cpoll =
        comm  + (size_t)b * NREC + (1 - n) * NHALF + pc;
    const unsigned long long* cpoll2 =
        comm2 + (size_t)b * NREC + (1 - n) * NHALF + pc;

    hl[tid] = (_Float16)0.f;                       // h_0 = 0 (512 entries)
    float hj = 0.f, inp = 0.f, nz = 0.f;
    if (tid < NHALF) { inp = io[iobase]; nz = noise[iobase]; }
    __syncthreads();

    for (int t = 0; t < T_STEPS; ++t) {
        // ---- A-fragments from hl: row 0 = h, rows 1-15 = 0 ----
        f16x8 af[8];
#pragma unroll
        for (int kt = 0; kt < 8; ++kt) {
            f16x8 a;
#pragma unroll
            for (int j = 0; j < 8; ++j) a[j] = (_Float16)0.f;
            if (lrow == 0)
                a = *reinterpret_cast<const f16x8*>(
                    &hl[kh * 256 + kt * 32 + lkb * 8]);
            af[kt] = a;
        }

        // ---- 32 MFMA: C[0][col] = sum_k h[k] * W[k][col] ----
        f32x4 cc[4];
#pragma unroll
        for (int nt = 0; nt < 4; ++nt) {
            cc[nt][0] = 0.f; cc[nt][1] = 0.f;
            cc[nt][2] = 0.f; cc[nt][3] = 0.f;
        }
#pragma unroll
        for (int kt = 0; kt < 8; ++kt)
#pragma unroll
            for (int nt = 0; nt < 4; ++nt)
                cc[nt] = __builtin_amdgcn_mfma_f32_16x16x32_f16(
                    af[kt], wf[kt][nt], cc[nt], 0, 0, 0);

        // ---- extract row 0 into part[kh] ----
        if (ln < 16) {
#pragma unroll
            for (int nt = 0; nt < 4; ++nt)
                part[kh][ns * 64 + nt * 16 + ln] = cc[nt][0];
        }
        LDS_BARRIER();                             // B1: partials ready

        if (tid < NHALF) {
            // ---- update own column; publish h_{t+1}; io row t ----
            float pre  = part[0][uc] + part[1][uc] + inp + nz;
            float hnew = (1.f - ALPHA) * hj + ALPHA * fmaxf(pre, 0.f);
            hj = hnew;
            hl[n * NHALF + uc] = (_Float16)hnew;
            if (t + 1 < T_STEPS) {
                unsigned long long pv =
                    ((unsigned long long)(unsigned)(t + 1) << 32) |
                    (unsigned long long)__float_as_uint(hnew);
                const size_t po = (size_t)((t + 1) & 1) * COMM_U64;
                st_l2(cwr2 + po, pv);              // XCD-local publish
                st_llc(cwr + po, pv);              // guaranteed publish
            }
            io[iobase + (size_t)t * NREC] = hnew;
            if (t + 1 < T_STEPS) {                 // prefetch next row
                inp = io[iobase + (size_t)(t + 1) * NREC];
                nz  = noise[iobase + (size_t)(t + 1) * NREC];
            }
        } else if (t + 1 < T_STEPS) {
            // ---- poll partner's h_{t+1}[pc]; deposit into hl ----
            const size_t po = (size_t)((t + 1) & 1) * COMM_U64;
            unsigned long long v = ld_l2(cpoll2 + po);
            while ((int)(unsigned)(v >> 32) < t + 1) {
                v = ld_llc(cpoll + po);            // safety net
                if ((int)(unsigned)(v >> 32) >= t + 1) break;
                v = ld_l2(cpoll2 + po);            // fast path
            }
            asm volatile("" ::: "memory");
            hl[(1 - n) * NHALF + pc] =
                (_Float16)__uint_as_float((unsigned)(v & 0xffffffffu));
        }
        LDS_BARRIER();                             // B2: hl ready for t+1
    }
}

// ---------------------------------------------------------------------------
// Fallback (round-1 kernel, fp32) if ws_size is too small.
// ---------------------------------------------------------------------------
__global__ __launch_bounds__(1024) void rnn_kernel(
        const float* __restrict__ W,
        const float* __restrict__ noise,
        float* __restrict__ io) {
    __shared__ float h[NREC];
    __shared__ float part2[NREC];

    const int tid  = threadIdx.x;
    const int j    = tid & (NREC - 1);
    const int half = tid >> 9;
    const int b    = blockIdx.x;

    if (tid < NREC) h[tid] = 0.f;
    float hj = 0.f;
    __syncthreads();

    const int kb = half * 256;
    const float* wp = W + (size_t)kb * NREC + j;
    const size_t base = (size_t)b * T_STEPS * NREC + j;

    for (int t = 0; t < T_STEPS; ++t) {
        const size_t off = base + (size_t)t * NREC;
        float acc = (half == 0) ? (io[off] + noise[off]) : 0.f;
#pragma unroll
        for (int ku = 0; ku < 256; ku += 16) {
            float wv[16];
#pragma unroll
            for (int u = 0; u < 16; ++u) wv[u] = wp[(size_t)(ku + u) * NREC];
#pragma unroll
            for (int u = 0; u < 16; ++u) acc = fmaf(h[kb + ku + u], wv[u], acc);
        }
        if (half == 1) part2[j] = acc;
        __syncthreads();
        if (half == 0) {
            float pre  = acc + part2[j];
            float hnew = (1.f - ALPHA) * hj + ALPHA * fmaxf(pre, 0.f);
            io[off] = hnew;
            h[j] = hnew;
            hj = hnew;
        }
        __syncthreads();
    }
}

// ---------------------------------------------------------------------------
extern "C" void kernel_launch(void* const* d_in, const int* in_sizes, int n_in,
                              void* d_out, int out_size, void* d_ws, size_t ws_size,
                              hipStream_t stream) {
    const float* x       = (const float*)d_in[0];
    const float* w_in    = (const float*)d_in[1];
    const float* w_rec   = (const float*)d_in[2];
    const float* b_rec   = (const float*)d_in[3];
    const float* ei_mask = (const float*)d_in[4];
    const float* autapse = (const float*)d_in[5];
    const float* noise   = (const float*)d_in[6];
    float* out = (float*)d_out;

    gemm_in_kernel<<<dim3(64000 / 32), dim3(1024), 0, stream>>>(
        x, w_in, b_rec, out);

    if (ws_size >= (size_t)WS_NEEDED) {
        _Float16* Wt = (_Float16*)d_ws;
        unsigned long long* comm  =
            (unsigned long long*)((char*)d_ws + WS_COMM_OFF);
        unsigned long long* comm2 =
            (unsigned long long*)((char*)d_ws + WS_COMM2_OFF);
        weff_f16_kernel<<<dim3((NREC * NREC + 255) / 256), dim3(256),
                          0, stream>>>(w_rec, ei_mask, autapse, Wt);
        hipMemsetAsync(comm, 0, 2 * COMM_BYTES, stream);   // reset tags
        void* args[] = {(void*)&Wt, (void*)&noise, (void*)&out,
                        (void*)&comm, (void*)&comm2};
        hipLaunchCooperativeKernel(reinterpret_cast<void*>(rnn_mfma2),
                                   dim3(NBATCH * 2), dim3(512),
                                   args, 0, stream);
    } else {
        float* W = (float*)d_ws;
        weff_kernel<<<dim3((NREC * NREC + 255) / 256), dim3(256),
                      0, stream>>>(w_rec, ei_mask, autapse, W);
        rnn_kernel<<<dim3(NBATCH), dim3(1024), 0, stream>>>(W, noise, out);
    }
}